// Round 3
// baseline (133.226 us; speedup 1.0000x reference)
//
#include <hip/hip_runtime.h>

// Forest-Ruth 4th-order symplectic, 25 steps. State: P (rad/s), Q (REVOLUTIONS).
// sin via two paths to use both issue pipes:
//   chains 0,1: hardware v_sin_f32 (trans pipe, measured ~16 cyc/wave-instr)
//   chains 2,3: packed degree-13 odd Taylor of sin(2*pi*r) on v_pk_* (VALU pipe)
// Range reduction: r = Q - rndne(Q) via the 1.5*2^23 magic-number trick (|Q|<~2).
// Poly truncation error at |r|=0.5 is 2.1e-5 << 0.149 threshold.

#define NSTEPS 25

typedef float v2f __attribute__((ext_vector_type(2)));

__device__ __forceinline__ v2f pk_fma(v2f a, v2f b, v2f c) {
    v2f d;
    asm("v_pk_fma_f32 %0, %1, %2, %3" : "=v"(d) : "v"(a), "v"(b), "v"(c));
    return d;
}
__device__ __forceinline__ v2f pk_add(v2f a, v2f b) {
    v2f d;
    asm("v_pk_add_f32 %0, %1, %2" : "=v"(d) : "v"(a), "v"(b));
    return d;
}
__device__ __forceinline__ v2f pk_mul(v2f a, v2f b) {
    v2f d;
    asm("v_pk_mul_f32 %0, %1, %2" : "=v"(d) : "v"(a), "v"(b));
    return d;
}

__global__ __launch_bounds__(256) void symp4_kernel(
    const float4* __restrict__ p0,
    const float4* __restrict__ q0,
    const float* __restrict__ t0,
    const float* __restrict__ t1,
    float4* __restrict__ out_p,
    float4* __restrict__ out_q,
    int nthreads)
{
    const int tid = blockIdx.x * blockDim.x + threadIdx.x;
    if (tid >= nthreads) return;

    const float h = (t1[0] - t0[0]) * (1.0f / (float)NSTEPS);

    const float INV2PI = 0.15915494309189535f;
    const float TWOPI  = 6.283185307179586f;

    // q-updates in revolution units; p-updates take sin() output directly
    const float c1hr =  0.10752506536265768f * h;  // c1/(2pi) * h
    const float c2hr = -0.02794866718106242f * h;  // c2/(2pi) * h
    const float nd1h = -1.3512071919596578f  * h;  // -(d1*h)
    const float nd2h =  1.7024143839193153f  * h;  // -(d2*h)

    const v2f c1v = {c1hr, c1hr};
    const v2f c2v = {c2hr, c2hr};
    const v2f d1v = {nd1h, nd1h};
    const v2f d2v = {nd2h, nd2h};

    // magic rndne constants and poly coefficients for sin(2*pi*r), r in [-.5,.5]
    const v2f Mv    = { 12582912.0f,  12582912.0f};   // 1.5 * 2^23
    const v2f Mnegv = {-12582912.0f, -12582912.0f};
    const v2f neg1v = {-1.0f, -1.0f};
    const v2f A1  = { 6.2831853071795865f,  6.2831853071795865f};
    const v2f A3  = {-41.341702240399755f, -41.341702240399755f};
    const v2f A5  = { 81.605249090578990f,  81.605249090578990f};
    const v2f A7  = {-76.705859750631180f, -76.705859750631180f};
    const v2f A9  = { 42.058693944897380f,  42.058693944897380f};
    const v2f A11 = {-15.094800000000000f, -15.094800000000000f};
    const v2f A13 = { 3.8199400000000000f,  3.8199400000000000f};

    float4 pa = p0[2 * tid], pb = p0[2 * tid + 1];
    float4 qa = q0[2 * tid], qb = q0[2 * tid + 1];

    v2f P[4] = {{pa.x, pa.y}, {pa.z, pa.w}, {pb.x, pb.y}, {pb.z, pb.w}};
    v2f Q[4] = {{qa.x * INV2PI, qa.y * INV2PI}, {qa.z * INV2PI, qa.w * INV2PI},
                {qb.x * INV2PI, qb.y * INV2PI}, {qb.z * INV2PI, qb.w * INV2PI}};

    // packed polynomial sin(2*pi*Q) for one v2f pair
    auto sinpk = [&](v2f Qj) -> v2f {
        v2f t = pk_add(Qj, Mv);        // rounds to nearest int (RNE)
        v2f n = pk_add(t, Mnegv);      // n = rndne(Qj)
        v2f r = pk_fma(n, neg1v, Qj);  // r = Qj - n, in [-0.5, 0.5]
        v2f u = pk_mul(r, r);
        v2f p = pk_fma(A13, u, A11);
        p = pk_fma(p, u, A9);
        p = pk_fma(p, u, A7);
        p = pk_fma(p, u, A5);
        p = pk_fma(p, u, A3);
        p = pk_fma(p, u, A1);
        return pk_mul(p, r);
    };

    for (int s = 0; s < NSTEPS; ++s) {
        #pragma unroll
        for (int sub = 0; sub < 4; ++sub) {
            const v2f cv = (sub == 0 || sub == 3) ? c1v : c2v;
            // q-update: all 4 chains, packed
            #pragma unroll
            for (int j = 0; j < 4; ++j) Q[j] = pk_fma(cv, P[j], Q[j]);
            if (sub == 3) continue;  // d4 = 0, no p-update
            const v2f dv = (sub == 1) ? d2v : d1v;
            const float nd = (sub == 1) ? nd2h : nd1h;
            // chains 0,1: hardware v_sin (trans pipe), scalar d-fma
            #pragma unroll
            for (int j = 0; j < 2; ++j) {
                P[j].x = fmaf(nd, __builtin_amdgcn_sinf(Q[j].x), P[j].x);
                P[j].y = fmaf(nd, __builtin_amdgcn_sinf(Q[j].y), P[j].y);
            }
            // chains 2,3: packed polynomial sin (VALU pipe)
            #pragma unroll
            for (int j = 2; j < 4; ++j) {
                P[j] = pk_fma(dv, sinpk(Q[j]), P[j]);
            }
        }
    }

    out_p[2 * tid]     = make_float4(P[0].x, P[0].y, P[1].x, P[1].y);
    out_p[2 * tid + 1] = make_float4(P[2].x, P[2].y, P[3].x, P[3].y);
    out_q[2 * tid]     = make_float4(Q[0].x * TWOPI, Q[0].y * TWOPI,
                                     Q[1].x * TWOPI, Q[1].y * TWOPI);
    out_q[2 * tid + 1] = make_float4(Q[2].x * TWOPI, Q[2].y * TWOPI,
                                     Q[3].x * TWOPI, Q[3].y * TWOPI);
}

extern "C" void kernel_launch(void* const* d_in, const int* in_sizes, int n_in,
                              void* d_out, int out_size, void* d_ws, size_t ws_size,
                              hipStream_t stream) {
    const float* p0 = (const float*)d_in[0];
    const float* q0 = (const float*)d_in[1];
    const float* t0 = (const float*)d_in[2];
    const float* t1 = (const float*)d_in[3];
    float* out = (float*)d_out;  // [kp (n) | kq (n)] flat, fp32

    const int n = in_sizes[0];        // 4194304, divisible by 8
    const int nthreads = n / 8;       // 524288
    const int block = 256;
    const int grid = (nthreads + block - 1) / block;  // 2048 blocks = 8/CU

    symp4_kernel<<<grid, block, 0, stream>>>(
        (const float4*)p0, (const float4*)q0, t0, t1,
        (float4*)out, (float4*)(out + n), nthreads);
}